// Round 9
// baseline (169.227 us; speedup 1.0000x reference)
//
#include <hip/hip_runtime.h>

#define FDIM 512
#define CDIM 64
#define NLEAF 1024
#define MAT (FDIM * CDIM)            /* 32768 floats per node */
#define OUT_LOGITS (NLEAF * CDIM)    /* 65536 */
#define WS_REG (6 * NLEAF * CDIM)    /* float offset of reg partials in ws */
#define XSTRIDE 576                  /* LDS x row stride: 16 fg * 36 */

__device__ __forceinline__ float abs4(const float4 v) {
    return fabsf(v.x) + fabsf(v.y) + fabsf(v.z) + fabsf(v.w);
}
__device__ __forceinline__ float sq4(const float4 v) {
    return v.x * v.x + v.y * v.y + v.z * v.z + v.w * v.w;
}

// ---------------------------------------------------------------------------
// One block = (node, tile of R descendant leaves). Streams the node's full
// 128KB slab once with the round-3-proven 4-deep float4 burst shape; x rows
// come from a bank-padded LDS tile (broadcast b128 reads). Logit partials
// are written non-atomically to ws[dIdx][row][c] (each written by exactly
// one block). Reg term folded in (scale=0 for non-owner tiles).
// MODE: 1 = L1*scale, 2 = squared (root owner tile).
// ---------------------------------------------------------------------------
template<int R, int MODE>
__device__ __forceinline__ void run_node(const float* __restrict__ x,
                                         const float* __restrict__ deltas,
                                         float* __restrict__ ws,
                                         int node, int row0, int dIdx, int bid,
                                         float scale,
                                         float* __restrict__ xl,
                                         float* __restrict__ red,
                                         float* __restrict__ rr)
{
    const int tid = threadIdx.x;
    const int fg  = tid >> 4;          // f-slice base = fg*32
    const int cq  = tid & 15;          // c-quad
    const int w   = tid >> 6;
    const int lane = tid & 63;

    // ---- stage x rows [row0, row0+R) into padded LDS (conflict-free reads)
    for (int idx = tid; idx < R * 128; idx += 256) {
        const int r = idx >> 7, t = idx & 127;
        const int fgp = t >> 3, j = t & 7;
        *(float4*)(xl + r * XSTRIDE + fgp * 36 + 4 * j) =
            *(const float4*)(x + (size_t)(row0 + r) * FDIM + fgp * 32 + 4 * j);
    }
    __syncthreads();

    const float* dbase = deltas + (size_t)node * MAT
                       + (size_t)fg * 32 * CDIM + (size_t)cq * 4;
    const float* xb = xl + fg * 36;

    float4 acc[R];
#pragma unroll
    for (int r = 0; r < R; ++r) acc[r] = make_float4(0.f, 0.f, 0.f, 0.f);
    float rsum = 0.f;

    // ---- stream the slab: 8 bursts x 4 f-rows (R3's proven 4-deep shape)
#pragma unroll
    for (int h = 0; h < 8; ++h) {
        const float* qp = dbase + (size_t)(4 * h) * CDIM;
        const float4 d0 = *(const float4*)(qp);
        const float4 d1 = *(const float4*)(qp + CDIM);
        const float4 d2 = *(const float4*)(qp + 2 * CDIM);
        const float4 d3 = *(const float4*)(qp + 3 * CDIM);
        if (MODE == 1) rsum = fmaf(abs4(d0) + abs4(d1) + abs4(d2) + abs4(d3), scale, rsum);
        if (MODE == 2) rsum += sq4(d0) + sq4(d1) + sq4(d2) + sq4(d3);
#pragma unroll
        for (int r = 0; r < R; ++r) {
            const float4 xv = *(const float4*)(xb + r * XSTRIDE + 4 * h);
            acc[r].x += xv.x * d0.x + xv.y * d1.x + xv.z * d2.x + xv.w * d3.x;
            acc[r].y += xv.x * d0.y + xv.y * d1.y + xv.z * d2.y + xv.w * d3.y;
            acc[r].z += xv.x * d0.z + xv.y * d1.z + xv.z * d2.z + xv.w * d3.z;
            acc[r].w += xv.x * d0.w + xv.y * d1.w + xv.z * d2.w + xv.w * d3.w;
        }
    }

    // ---- reduce over the 4 fg per wave (lane bits 4,5)
#pragma unroll
    for (int r = 0; r < R; ++r) {
        acc[r].x += __shfl_xor(acc[r].x, 16, 64);  acc[r].x += __shfl_xor(acc[r].x, 32, 64);
        acc[r].y += __shfl_xor(acc[r].y, 16, 64);  acc[r].y += __shfl_xor(acc[r].y, 32, 64);
        acc[r].z += __shfl_xor(acc[r].z, 16, 64);  acc[r].z += __shfl_xor(acc[r].z, 32, 64);
        acc[r].w += __shfl_xor(acc[r].w, 16, 64);  acc[r].w += __shfl_xor(acc[r].w, 32, 64);
    }

    constexpr int RS = 4 * R + 4;
    if (lane < 16) {
#pragma unroll
        for (int r = 0; r < R; ++r)
            *(float4*)(red + (w * 16 + cq) * RS + r * 4) = acc[r];
    }

    // ---- reg partial: wave butterfly -> LDS
#pragma unroll
    for (int off = 1; off < 64; off <<= 1) rsum += __shfl_xor(rsum, off, 64);
    if (lane == 0) rr[w] = rsum;
    __syncthreads();

    // ---- write R*64 logit partials (each (dIdx,row,c) owned by this block)
    for (int idx = tid; idx < R * 64; idx += 256) {
        const int r = idx >> 6, c = idx & 63;
        float s = 0.f;
#pragma unroll
        for (int w2 = 0; w2 < 4; ++w2)
            s += red[(w2 * 16 + (c >> 2)) * RS + r * 4 + (c & 3)];
        ws[(size_t)dIdx * OUT_LOGITS + (size_t)(row0 + r) * CDIM + c] = s;
    }
    if (tid == 0)
        ws[WS_REG + bid] = rr[0] + rr[1] + rr[2] + rr[3];
}

__global__ __launch_bounds__(256, 4) void k_stream(const float* __restrict__ x,
                                                   const float* __restrict__ deltas,
                                                   const float* __restrict__ heights,
                                                   float* __restrict__ ws)
{
    __shared__ float xl[8 * XSTRIDE];    // 18.4 KB padded x tile
    __shared__ float red[64 * 36];       // 9.2 KB reduction buffer
    __shared__ float rr[4];

    const int bid = blockIdx.x;

    if (bid < 1024) {                    // ---- leaves, XCD-swizzled
        const int b = ((bid & 7) << 7) | (bid >> 3);
        const int node = 341 + b;
        const float s = 1.f / fmaxf(fabsf(heights[node] - heights[85 + (b >> 2)]), 1e-7f);
        run_node<1, 1>(x, deltas, ws, node, b, 5, bid, s, xl, red, rr);
    } else if (bid < 1280) {             // ---- depth 4 (every block owns reg)
        const int q = bid - 1024;
        const int node = 85 + q;
        const float s = 1.f / fmaxf(fabsf(heights[node] - heights[21 + (q >> 2)]), 1e-7f);
        run_node<4, 1>(x, deltas, ws, node, 4 * q, 4, bid, s, xl, red, rr);
    } else if (bid < 1408) {             // ---- depth 3: 2 tiles/node
        const int q = bid - 1280;
        const int node = 21 + (q >> 1);
        const float s = ((q & 1) == 0)
            ? 1.f / fmaxf(fabsf(heights[node] - heights[5 + ((q >> 1) >> 2)]), 1e-7f) : 0.f;
        run_node<8, 1>(x, deltas, ws, node, 8 * q, 3, bid, s, xl, red, rr);
    } else if (bid < 1536) {             // ---- depth 2: 8 tiles/node
        const int q = bid - 1408;
        const int node = 5 + (q >> 3);
        const float s = ((q & 7) == 0)
            ? 1.f / fmaxf(fabsf(heights[node] - heights[1 + ((q >> 3) >> 2)]), 1e-7f) : 0.f;
        run_node<8, 1>(x, deltas, ws, node, 8 * q, 2, bid, s, xl, red, rr);
    } else if (bid < 1664) {             // ---- depth 1: 32 tiles/node
        const int q = bid - 1536;
        const int node = 1 + (q >> 5);
        const float s = ((q & 31) == 0)
            ? 1.f / fmaxf(fabsf(heights[node] - heights[0]), 1e-7f) : 0.f;
        run_node<8, 1>(x, deltas, ws, node, 8 * q, 1, bid, s, xl, red, rr);
    } else {                             // ---- root: 128 tiles
        const int q = bid - 1664;
        if (q == 0) run_node<8, 2>(x, deltas, ws, 0, 0,     0, bid, 0.f, xl, red, rr);
        else        run_node<8, 1>(x, deltas, ws, 0, 8 * q, 0, bid, 0.f, xl, red, rr);
    }
}

// ---------------------------------------------------------------------------
// Finish: sum the 6 depth-partials per leaf row, softmax, write out.
// One 64-lane wave per row; 256 blocks x 256 threads.
// ---------------------------------------------------------------------------
__global__ __launch_bounds__(256) void k_finish(const float* __restrict__ ws,
                                                float* __restrict__ out)
{
    const int l = blockIdx.x * 4 + (threadIdx.x >> 6);
    const int c = threadIdx.x & 63;
    const size_t o = (size_t)l * CDIM + c;
    float v = 0.f;
#pragma unroll
    for (int d = 0; d < 6; ++d) v += ws[(size_t)d * OUT_LOGITS + o];
    float m = v;
#pragma unroll
    for (int off = 32; off > 0; off >>= 1) m = fmaxf(m, __shfl_xor(m, off, 64));
    const float e = expf(v - m);
    float s = e;
#pragma unroll
    for (int off = 32; off > 0; off >>= 1) s += __shfl_xor(s, off, 64);
    out[o] = e / s;
}

// ---------------------------------------------------------------------------
// Sum the 1792 reg partials -> out[OUT_LOGITS]
// ---------------------------------------------------------------------------
__global__ __launch_bounds__(256) void k_regsum(const float* __restrict__ ws,
                                                float* __restrict__ out)
{
    __shared__ float r[4];
    const int tid = threadIdx.x;
    const float* p = ws + WS_REG;
    float v = 0.f;
#pragma unroll
    for (int i = 0; i < 7; ++i) v += p[i * 256 + tid];   // 7*256 = 1792
#pragma unroll
    for (int off = 1; off < 64; off <<= 1) v += __shfl_xor(v, off, 64);
    if ((tid & 63) == 0) r[tid >> 6] = v;
    __syncthreads();
    if (tid == 0) out[OUT_LOGITS] = r[0] + r[1] + r[2] + r[3];
}

extern "C" void kernel_launch(void* const* d_in, const int* in_sizes, int n_in,
                              void* d_out, int out_size, void* d_ws, size_t ws_size,
                              hipStream_t stream)
{
    const float* x       = (const float*)d_in[0];
    const float* deltas  = (const float*)d_in[1];
    const float* heights = (const float*)d_in[2];
    float* out = (float*)d_out;
    float* ws  = (float*)d_ws;

    k_stream<<<1792, 256, 0, stream>>>(x, deltas, heights, ws);
    k_finish<<<256, 256, 0, stream>>>(ws, out);
    k_regsum<<<1, 256, 0, stream>>>(ws, out);
}

// Round 10
// 74.738 us; speedup vs baseline: 2.2643x; 2.2643x over previous
//
#include <hip/hip_runtime.h>

#define FDIM 512
#define CDIM 64
#define NLEAF 1024
#define MAT (FDIM * CDIM)          /* 32768 floats per node */
#define OUT_LOGITS (NLEAF * CDIM)  /* 65536 */
#define WS_REG (NLEAF * CDIM)      /* float offset of reg partials in ws */

__device__ __forceinline__ float abs4(const float4 v) {
    return fabsf(v.x) + fabsf(v.y) + fabsf(v.z) + fabsf(v.w);
}
__device__ __forceinline__ float sq4(const float4 v) {
    return v.x * v.x + v.y * v.y + v.z * v.z + v.w * v.w;
}

// Shared-ancestor stream: this thread's 16f x 4c (c-half) tile of one node,
// 4 bursts x 4-deep (R3's proven shape); FMA into BOTH leaves' accs.
// MODE: 0 = none, 1 = L1*scale, 2 = squared (root)
template<int MODE>
__device__ __forceinline__ void stream2(const float* __restrict__ dbase,
                                        const float4 xr[2][4],
                                        float4* __restrict__ acc,
                                        float& rsum, float s)
{
#pragma unroll
    for (int h = 0; h < 4; ++h) {
        const float* q = dbase + (size_t)(4 * h) * CDIM;
        const float4 d0 = *(const float4*)(q);
        const float4 d1 = *(const float4*)(q + CDIM);
        const float4 d2 = *(const float4*)(q + 2 * CDIM);
        const float4 d3 = *(const float4*)(q + 3 * CDIM);
        if (MODE == 1) rsum = fmaf(abs4(d0) + abs4(d1) + abs4(d2) + abs4(d3), s, rsum);
        if (MODE == 2) rsum += sq4(d0) + sq4(d1) + sq4(d2) + sq4(d3);
#pragma unroll
        for (int r = 0; r < 2; ++r) {
            const float4 xv = xr[r][h];
            acc[r].x += xv.x * d0.x + xv.y * d1.x + xv.z * d2.x + xv.w * d3.x;
            acc[r].y += xv.x * d0.y + xv.y * d1.y + xv.z * d2.y + xv.w * d3.y;
            acc[r].z += xv.x * d0.z + xv.y * d1.z + xv.z * d2.z + xv.w * d3.z;
            acc[r].w += xv.x * d0.w + xv.y * d1.w + xv.z * d2.w + xv.w * d3.w;
        }
    }
}

// Leaf stream: same shape, FMA into acc[R] only; always reg-owner (L1*scale).
template<int R>
__device__ __forceinline__ void stream1(const float* __restrict__ dbase,
                                        const float4 xr[2][4],
                                        float4* __restrict__ acc,
                                        float& rsum, float s)
{
#pragma unroll
    for (int h = 0; h < 4; ++h) {
        const float* q = dbase + (size_t)(4 * h) * CDIM;
        const float4 d0 = *(const float4*)(q);
        const float4 d1 = *(const float4*)(q + CDIM);
        const float4 d2 = *(const float4*)(q + 2 * CDIM);
        const float4 d3 = *(const float4*)(q + 3 * CDIM);
        rsum = fmaf(abs4(d0) + abs4(d1) + abs4(d2) + abs4(d3), s, rsum);
        const float4 xv = xr[R][h];
        acc[R].x += xv.x * d0.x + xv.y * d1.x + xv.z * d2.x + xv.w * d3.x;
        acc[R].y += xv.x * d0.y + xv.y * d1.y + xv.z * d2.y + xv.w * d3.y;
        acc[R].z += xv.x * d0.z + xv.y * d1.z + xv.z * d2.z + xv.w * d3.z;
        acc[R].w += xv.x * d0.w + xv.y * d1.w + xv.z * d2.w + xv.w * d3.w;
    }
}

// ---------------------------------------------------------------------------
// One block = (sibling leaf PAIR) x (c-half). 1024 blocks, 4/CU — identical
// grid, burst shape, coalescing (128B segments), phase order and XCD
// topology to the round-3 winner, but the 5 shared ancestors are streamed
// once per PAIR: total L2-side demand 393 MB vs R3's 786 MB.
// Thread tile: 16 f x 4 c; per-thread state ~85 VGPR (fits 128 cap).
// ---------------------------------------------------------------------------
__global__ __launch_bounds__(256, 4) void k_fused(const float* __restrict__ x,
                                                  const float* __restrict__ deltas,
                                                  const float* __restrict__ heights,
                                                  float* __restrict__ ws)
{
    __shared__ float red[4 * 64];   // [wave][r*32 + cq*4 + comp]
    __shared__ float rr[4];

    const int tid = threadIdx.x;
    const int bid = blockIdx.x;
    // XCD k owns pairs [64k,64k+64) = leaves [128k,128k+128); both c-halves
    // of a pair are dispatch-adjacent on the same XCD.
    const int k  = bid & 7;
    const int t  = bid >> 3;            // 0..127
    const int p  = (k << 6) | (t >> 1); // pair 0..511
    const int ch = t & 1;               // c-half
    const int l0 = 2 * p;               // first leaf of pair
    const int fg = tid >> 3;            // 0..31 (16 f each)
    const int cq = tid & 7;             // c-quad within half
    const int c0 = ch * 32 + cq * 4;

    // x fragments: 2 leaves x 16 f = 8 float4
    float4 xr[2][4];
#pragma unroll
    for (int r = 0; r < 2; ++r)
#pragma unroll
        for (int j = 0; j < 4; ++j)
            xr[r][j] = *(const float4*)(x + (size_t)(l0 + r) * FDIM + fg * 16 + 4 * j);

    float4 acc[2];
    acc[0] = make_float4(0.f, 0.f, 0.f, 0.f);
    acc[1] = make_float4(0.f, 0.f, 0.f, 0.f);
    float rsum = 0.f;
    const size_t toff = (size_t)(fg * 16) * CDIM + c0;

    // ---- shared ancestors root -> depth 4 (R3's branchy runtime loop)
#pragma unroll
    for (int d = 0; d < 5; ++d) {
        const int shift = 2 * (5 - d);
        const int start = ((1 << (2 * d)) - 1) / 3;   // 0,1,5,21,85
        const int node  = start + (l0 >> shift);
        const float* dbase = deltas + (size_t)node * MAT + toff;
        const bool doReg = (l0 & ((1 << shift) - 1)) == 0;
        if (d == 0) {
            if (doReg) stream2<2>(dbase, xr, acc, rsum, 1.f);
            else       stream2<0>(dbase, xr, acc, rsum, 0.f);
        } else {
            if (doReg) {
                const int par = (node - 1) >> 2;
                const float s = 1.f / fmaxf(fabsf(heights[node] - heights[par]), 1e-7f);
                stream2<1>(dbase, xr, acc, rsum, s);
            } else {
                stream2<0>(dbase, xr, acc, rsum, 0.f);
            }
        }
    }

    // ---- the two leaf slabs (c-half each); barrier bounds load hoisting
    {
        const int n5 = 341 + l0;
        const float hp = heights[85 + (l0 >> 2)];
        const float sA = 1.f / fmaxf(fabsf(heights[n5]     - hp), 1e-7f);
        stream1<0>(deltas + (size_t)n5 * MAT + toff, xr, acc, rsum, sA);
        __builtin_amdgcn_sched_barrier(0);
        const float sB = 1.f / fmaxf(fabsf(heights[n5 + 1] - hp), 1e-7f);
        stream1<1>(deltas + (size_t)(n5 + 1) * MAT + toff, xr, acc, rsum, sB);
    }

    // ---- reduce over fg within wave (fg spans lane bits 3,4,5)
#pragma unroll
    for (int r = 0; r < 2; ++r) {
        acc[r].x += __shfl_xor(acc[r].x, 8, 64); acc[r].x += __shfl_xor(acc[r].x, 16, 64); acc[r].x += __shfl_xor(acc[r].x, 32, 64);
        acc[r].y += __shfl_xor(acc[r].y, 8, 64); acc[r].y += __shfl_xor(acc[r].y, 16, 64); acc[r].y += __shfl_xor(acc[r].y, 32, 64);
        acc[r].z += __shfl_xor(acc[r].z, 8, 64); acc[r].z += __shfl_xor(acc[r].z, 16, 64); acc[r].z += __shfl_xor(acc[r].z, 32, 64);
        acc[r].w += __shfl_xor(acc[r].w, 8, 64); acc[r].w += __shfl_xor(acc[r].w, 16, 64); acc[r].w += __shfl_xor(acc[r].w, 32, 64);
    }

    const int w = tid >> 6, lane = tid & 63;
    if (lane < 8) {   // lane == cq
#pragma unroll
        for (int r = 0; r < 2; ++r)
            *(float4*)(red + w * 64 + r * 32 + cq * 4) = acc[r];
    }

    // ---- reg partial: full-wave butterfly -> LDS
#pragma unroll
    for (int off = 1; off < 64; off <<= 1) rsum += __shfl_xor(rsum, off, 64);
    if (lane == 0) rr[w] = rsum;
    __syncthreads();

    // ---- write the 64 complete logits this block owns (f fully reduced)
    if (tid < 64) {
        const int r = tid >> 5, cc = tid & 31;
        const float v = red[0 * 64 + r * 32 + cc] + red[1 * 64 + r * 32 + cc]
                      + red[2 * 64 + r * 32 + cc] + red[3 * 64 + r * 32 + cc];
        ws[(size_t)(l0 + r) * CDIM + ch * 32 + cc] = v;
    }
    if (tid == 64)
        ws[WS_REG + bid] = rr[0] + rr[1] + rr[2] + rr[3];
}

// ---------------------------------------------------------------------------
// Finish: softmax per leaf row (logits complete in ws). One wave per row.
// ---------------------------------------------------------------------------
__global__ __launch_bounds__(256) void k_finish(const float* __restrict__ ws,
                                                float* __restrict__ out)
{
    const int l = blockIdx.x * 4 + (threadIdx.x >> 6);
    const int c = threadIdx.x & 63;
    const float v = ws[(size_t)l * CDIM + c];
    float m = v;
#pragma unroll
    for (int off = 32; off > 0; off >>= 1) m = fmaxf(m, __shfl_xor(m, off, 64));
    const float e = expf(v - m);
    float s = e;
#pragma unroll
    for (int off = 32; off > 0; off >>= 1) s += __shfl_xor(s, off, 64);
    out[(size_t)l * CDIM + c] = e / s;
}

// ---------------------------------------------------------------------------
// Sum the 1024 reg partials -> out[OUT_LOGITS]
// ---------------------------------------------------------------------------
__global__ __launch_bounds__(256) void k_regsum(const float* __restrict__ ws,
                                                float* __restrict__ out)
{
    __shared__ float r[4];
    const int tid = threadIdx.x;
    const float* p = ws + WS_REG;
    float v = p[tid] + p[256 + tid] + p[512 + tid] + p[768 + tid];
#pragma unroll
    for (int off = 1; off < 64; off <<= 1) v += __shfl_xor(v, off, 64);
    if ((tid & 63) == 0) r[tid >> 6] = v;
    __syncthreads();
    if (tid == 0) out[OUT_LOGITS] = r[0] + r[1] + r[2] + r[3];
}

extern "C" void kernel_launch(void* const* d_in, const int* in_sizes, int n_in,
                              void* d_out, int out_size, void* d_ws, size_t ws_size,
                              hipStream_t stream)
{
    const float* x       = (const float*)d_in[0];
    const float* deltas  = (const float*)d_in[1];
    const float* heights = (const float*)d_in[2];
    float* out = (float*)d_out;
    float* ws  = (float*)d_ws;

    k_fused<<<NLEAF, 256, 0, stream>>>(x, deltas, heights, ws);
    k_finish<<<256, 256, 0, stream>>>(ws, out);
    k_regsum<<<1, 256, 0, stream>>>(ws, out);
}

// Round 11
// 39.240 us; speedup vs baseline: 4.3126x; 1.9046x over previous
//
#include <hip/hip_runtime.h>

#define FDIM 512
#define CDIM 64
#define NLEAF 1024
#define MAT (FDIM * CDIM)          /* 32768 floats per node */
#define OUT_LOGITS (NLEAF * CDIM)  /* 65536 */
#define WS_REG (NLEAF * CDIM)      /* float offset of reg partials in ws */

__device__ __forceinline__ float abs4(const float4 v) {
    return fabsf(v.x) + fabsf(v.y) + fabsf(v.z) + fabsf(v.w);
}
__device__ __forceinline__ float sq4(const float4 v) {
    return v.x * v.x + v.y * v.y + v.z * v.z + v.w * v.w;
}

// Shared-ancestor stream: this thread's 16f x 4c (c-half) tile of one node,
// 4 bursts x 4-deep (R3's proven shape); FMA into BOTH leaves' accs.
// MODE: 0 = none, 1 = L1*scale, 2 = squared (root)
template<int MODE>
__device__ __forceinline__ void stream2(const float* __restrict__ dbase,
                                        const float4 xr[2][4],
                                        float4* __restrict__ acc,
                                        float& rsum, float s)
{
#pragma unroll
    for (int h = 0; h < 4; ++h) {
        const float* q = dbase + (size_t)(4 * h) * CDIM;
        const float4 d0 = *(const float4*)(q);
        const float4 d1 = *(const float4*)(q + CDIM);
        const float4 d2 = *(const float4*)(q + 2 * CDIM);
        const float4 d3 = *(const float4*)(q + 3 * CDIM);
        if (MODE == 1) rsum = fmaf(abs4(d0) + abs4(d1) + abs4(d2) + abs4(d3), s, rsum);
        if (MODE == 2) rsum += sq4(d0) + sq4(d1) + sq4(d2) + sq4(d3);
#pragma unroll
        for (int r = 0; r < 2; ++r) {
            const float4 xv = xr[r][h];
            acc[r].x += xv.x * d0.x + xv.y * d1.x + xv.z * d2.x + xv.w * d3.x;
            acc[r].y += xv.x * d0.y + xv.y * d1.y + xv.z * d2.y + xv.w * d3.y;
            acc[r].z += xv.x * d0.z + xv.y * d1.z + xv.z * d2.z + xv.w * d3.z;
            acc[r].w += xv.x * d0.w + xv.y * d1.w + xv.z * d2.w + xv.w * d3.w;
        }
    }
}

// Leaf stream: same shape, FMA into acc[R] only; always reg-owner (L1*scale).
template<int R>
__device__ __forceinline__ void stream1(const float* __restrict__ dbase,
                                        const float4 xr[2][4],
                                        float4* __restrict__ acc,
                                        float& rsum, float s)
{
#pragma unroll
    for (int h = 0; h < 4; ++h) {
        const float* q = dbase + (size_t)(4 * h) * CDIM;
        const float4 d0 = *(const float4*)(q);
        const float4 d1 = *(const float4*)(q + CDIM);
        const float4 d2 = *(const float4*)(q + 2 * CDIM);
        const float4 d3 = *(const float4*)(q + 3 * CDIM);
        rsum = fmaf(abs4(d0) + abs4(d1) + abs4(d2) + abs4(d3), s, rsum);
        const float4 xv = xr[R][h];
        acc[R].x += xv.x * d0.x + xv.y * d1.x + xv.z * d2.x + xv.w * d3.x;
        acc[R].y += xv.x * d0.y + xv.y * d1.y + xv.z * d2.y + xv.w * d3.y;
        acc[R].z += xv.x * d0.z + xv.y * d1.z + xv.z * d2.z + xv.w * d3.z;
        acc[R].w += xv.x * d0.w + xv.y * d1.w + xv.z * d2.w + xv.w * d3.w;
    }
}

// ---------------------------------------------------------------------------
// One block = (sibling leaf PAIR) x (c-half). 1024 blocks, 4/CU — identical
// to round 10 except __launch_bounds__(256, 2): the (256,4) bound made the
// allocator cap at 64 VGPR and spill ~90 VGPRs of live state (80 MB scratch
// writes). (256,2) admits ~128 VGPR; residency stays 4 blocks/CU (grid-
// limited), 16 waves/CU — same as the R3 winner.
// Demand: 5 shared ancestors streamed once per PAIR -> 393 MB L2-side
// vs R3's 786 MB.
// ---------------------------------------------------------------------------
__global__ __launch_bounds__(256, 2) void k_fused(const float* __restrict__ x,
                                                  const float* __restrict__ deltas,
                                                  const float* __restrict__ heights,
                                                  float* __restrict__ ws)
{
    __shared__ float red[4 * 64];   // [wave][r*32 + cq*4 + comp]
    __shared__ float rr[4];

    const int tid = threadIdx.x;
    const int bid = blockIdx.x;
    // XCD k owns pairs [64k,64k+64) = leaves [128k,128k+128); both c-halves
    // of a pair are dispatch-adjacent on the same XCD.
    const int k  = bid & 7;
    const int t  = bid >> 3;            // 0..127
    const int p  = (k << 6) | (t >> 1); // pair 0..511
    const int ch = t & 1;               // c-half
    const int l0 = 2 * p;               // first leaf of pair
    const int fg = tid >> 3;            // 0..31 (16 f each)
    const int cq = tid & 7;             // c-quad within half
    const int c0 = ch * 32 + cq * 4;

    // x fragments: 2 leaves x 16 f = 8 float4
    float4 xr[2][4];
#pragma unroll
    for (int r = 0; r < 2; ++r)
#pragma unroll
        for (int j = 0; j < 4; ++j)
            xr[r][j] = *(const float4*)(x + (size_t)(l0 + r) * FDIM + fg * 16 + 4 * j);

    float4 acc[2];
    acc[0] = make_float4(0.f, 0.f, 0.f, 0.f);
    acc[1] = make_float4(0.f, 0.f, 0.f, 0.f);
    float rsum = 0.f;
    const size_t toff = (size_t)(fg * 16) * CDIM + c0;

    // ---- shared ancestors root -> depth 4 (R3's branchy runtime loop)
#pragma unroll
    for (int d = 0; d < 5; ++d) {
        const int shift = 2 * (5 - d);
        const int start = ((1 << (2 * d)) - 1) / 3;   // 0,1,5,21,85
        const int node  = start + (l0 >> shift);
        const float* dbase = deltas + (size_t)node * MAT + toff;
        const bool doReg = (l0 & ((1 << shift) - 1)) == 0;
        if (d == 0) {
            if (doReg) stream2<2>(dbase, xr, acc, rsum, 1.f);
            else       stream2<0>(dbase, xr, acc, rsum, 0.f);
        } else {
            if (doReg) {
                const int par = (node - 1) >> 2;
                const float s = 1.f / fmaxf(fabsf(heights[node] - heights[par]), 1e-7f);
                stream2<1>(dbase, xr, acc, rsum, s);
            } else {
                stream2<0>(dbase, xr, acc, rsum, 0.f);
            }
        }
    }

    // ---- the two leaf slabs (c-half each); barrier bounds load hoisting
    {
        const int n5 = 341 + l0;
        const float hp = heights[85 + (l0 >> 2)];
        const float sA = 1.f / fmaxf(fabsf(heights[n5]     - hp), 1e-7f);
        stream1<0>(deltas + (size_t)n5 * MAT + toff, xr, acc, rsum, sA);
        __builtin_amdgcn_sched_barrier(0);
        const float sB = 1.f / fmaxf(fabsf(heights[n5 + 1] - hp), 1e-7f);
        stream1<1>(deltas + (size_t)(n5 + 1) * MAT + toff, xr, acc, rsum, sB);
    }

    // ---- reduce over fg within wave (fg spans lane bits 3,4,5)
#pragma unroll
    for (int r = 0; r < 2; ++r) {
        acc[r].x += __shfl_xor(acc[r].x, 8, 64); acc[r].x += __shfl_xor(acc[r].x, 16, 64); acc[r].x += __shfl_xor(acc[r].x, 32, 64);
        acc[r].y += __shfl_xor(acc[r].y, 8, 64); acc[r].y += __shfl_xor(acc[r].y, 16, 64); acc[r].y += __shfl_xor(acc[r].y, 32, 64);
        acc[r].z += __shfl_xor(acc[r].z, 8, 64); acc[r].z += __shfl_xor(acc[r].z, 16, 64); acc[r].z += __shfl_xor(acc[r].z, 32, 64);
        acc[r].w += __shfl_xor(acc[r].w, 8, 64); acc[r].w += __shfl_xor(acc[r].w, 16, 64); acc[r].w += __shfl_xor(acc[r].w, 32, 64);
    }

    const int w = tid >> 6, lane = tid & 63;
    if (lane < 8) {   // lane == cq
#pragma unroll
        for (int r = 0; r < 2; ++r)
            *(float4*)(red + w * 64 + r * 32 + cq * 4) = acc[r];
    }

    // ---- reg partial: full-wave butterfly -> LDS
#pragma unroll
    for (int off = 1; off < 64; off <<= 1) rsum += __shfl_xor(rsum, off, 64);
    if (lane == 0) rr[w] = rsum;
    __syncthreads();

    // ---- write the 64 complete logits this block owns (f fully reduced)
    if (tid < 64) {
        const int r = tid >> 5, cc = tid & 31;
        const float v = red[0 * 64 + r * 32 + cc] + red[1 * 64 + r * 32 + cc]
                      + red[2 * 64 + r * 32 + cc] + red[3 * 64 + r * 32 + cc];
        ws[(size_t)(l0 + r) * CDIM + ch * 32 + cc] = v;
    }
    if (tid == 64)
        ws[WS_REG + bid] = rr[0] + rr[1] + rr[2] + rr[3];
}

// ---------------------------------------------------------------------------
// Finish: softmax per leaf row (logits complete in ws). One wave per row.
// ---------------------------------------------------------------------------
__global__ __launch_bounds__(256) void k_finish(const float* __restrict__ ws,
                                                float* __restrict__ out)
{
    const int l = blockIdx.x * 4 + (threadIdx.x >> 6);
    const int c = threadIdx.x & 63;
    const float v = ws[(size_t)l * CDIM + c];
    float m = v;
#pragma unroll
    for (int off = 32; off > 0; off >>= 1) m = fmaxf(m, __shfl_xor(m, off, 64));
    const float e = expf(v - m);
    float s = e;
#pragma unroll
    for (int off = 32; off > 0; off >>= 1) s += __shfl_xor(s, off, 64);
    out[(size_t)l * CDIM + c] = e / s;
}

// ---------------------------------------------------------------------------
// Sum the 1024 reg partials -> out[OUT_LOGITS]
// ---------------------------------------------------------------------------
__global__ __launch_bounds__(256) void k_regsum(const float* __restrict__ ws,
                                                float* __restrict__ out)
{
    __shared__ float r[4];
    const int tid = threadIdx.x;
    const float* p = ws + WS_REG;
    float v = p[tid] + p[256 + tid] + p[512 + tid] + p[768 + tid];
#pragma unroll
    for (int off = 1; off < 64; off <<= 1) v += __shfl_xor(v, off, 64);
    if ((tid & 63) == 0) r[tid >> 6] = v;
    __syncthreads();
    if (tid == 0) out[OUT_LOGITS] = r[0] + r[1] + r[2] + r[3];
}

extern "C" void kernel_launch(void* const* d_in, const int* in_sizes, int n_in,
                              void* d_out, int out_size, void* d_ws, size_t ws_size,
                              hipStream_t stream)
{
    const float* x       = (const float*)d_in[0];
    const float* deltas  = (const float*)d_in[1];
    const float* heights = (const float*)d_in[2];
    float* out = (float*)d_out;
    float* ws  = (float*)d_ws;

    k_fused<<<NLEAF, 256, 0, stream>>>(x, deltas, heights, ws);
    k_finish<<<256, 256, 0, stream>>>(ws, out);
    k_regsum<<<1, 256, 0, stream>>>(ws, out);
}